// Round 17
// baseline (266.151 us; speedup 1.0000x reference)
//
#include <hip/hip_runtime.h>

// MADE / PixelCNN autoregressive inverse (all fp32, per reference).
//
// Ledger: r7 146.5 / r11 137.8 (2-barrier, 8-wave). r13 143.9. r16
// spin-flags 157.4 (passed) -> the cost is not s_barrier, it's the
// CROSS-WAVE HANDOFF (~300-500cy each), and r11/r16 put 3-4 on the
// per-pixel critical path (the 1-px-slack W-tap handoffs).
//
// r17: spine computes everything except N-taps. W-taps = spine's OWN
// previous outputs: W1W.h0(p-1) via DOTU on its own h0row write (pad col
// 0 auto-zeroes j=0); centers via readlane on own h0v/h1v regs. Only the
// N-tap sums (row i-1, >=7-px slack) come from one helper wave per net;
// the spine's poll(hf>=p) hits data produced ~7 px earlier -> no wait.
// 4 waves (S-mu,S-lv,H-mu,H-lv), waves_per_eu(1,1) = 512-reg budget each
// (spine ~280 floats, helper ~414; r10 precedent: clean at this occupancy;
// NO asm pins per r12/r14). Cross-net xchg 2-deep + N-tap buffers 16-deep
// (r16-proven; re-proof: helper writes slot p+16 only after f0 >= p+2,
// i.e. after the spine consumed slot p). Bounded polls -> no hangs.

#define NT 256

__device__ __forceinline__ float elu(float x) { return x > 0.f ? x : expm1f(x); }

__device__ __forceinline__ float rdlane(float v, int l) {
  return __int_as_float(__builtin_amdgcn_readlane(__float_as_int(v), l));
}

__device__ __forceinline__ void poll_ge(volatile int* f, int v) {
  int g = 0;
  while (*f < v) { if (++g > (1 << 22)) break; }
  asm volatile("" ::: "memory");
  __builtin_amdgcn_sched_barrier(0);
}

__device__ __forceinline__ void set_flag(volatile int* f, int v, bool lane0) {
  asm volatile("s_waitcnt lgkmcnt(0)" ::: "memory");
  if (lane0) *f = v;
}

// 64-dot, activations broadcast via wave-uniform LDS float4 reads
#define DOTU(W_, B_)                                                  \
  _Pragma("unroll")                                                   \
  for (int q = 0; q < 16; ++q) {                                      \
    const float4 hq = *reinterpret_cast<const float4*>((B_) + 4*q);   \
    a0 += (W_)[4*q+0] * hq.x;                                         \
    a1 += (W_)[4*q+1] * hq.y;                                         \
    a2 += (W_)[4*q+2] * hq.z;                                         \
    a3 += (W_)[4*q+3] * hq.w;                                         \
  }

__global__ __launch_bounds__(NT)
__attribute__((amdgpu_waves_per_eu(1, 1)))
void made_ar_decode_k(
    const float* __restrict__ x,
    const float* __restrict__ mw0, const float* __restrict__ mb0,
    const float* __restrict__ mw1, const float* __restrict__ mb1,
    const float* __restrict__ mw2, const float* __restrict__ mb2,
    const float* __restrict__ mwo, const float* __restrict__ mbo,
    const float* __restrict__ lw0, const float* __restrict__ lb0,
    const float* __restrict__ lw1, const float* __restrict__ lb1,
    const float* __restrict__ lw2, const float* __restrict__ lb2,
    const float* __restrict__ lwo, const float* __restrict__ lbo,
    float* __restrict__ out)
{
  const int b    = blockIdx.x;
  const int tid  = threadIdx.x;
  const int wv   = tid >> 6;       // 0:S-mu 1:S-lv 2:H-mu 3:H-lv
  const int net  = wv & 1;
  const int role = wv >> 1;        // 0:S  1:H
  const int ch   = tid & 63;       // lane == out channel

  // row caches parity-buffered by row; pcol = spatial col + 1; pads 0,9
  // never written -> permanent zeros ('SAME' border + j=0 W-taps).
  __shared__ __align__(16) float h0row[2][2][10][64]; // [net][i&1][pcol][ch]
  __shared__ __align__(16) float h1row[2][2][10][64];
  __shared__ __align__(16) float yb[2][9][10][4];     // per-net copy
  __shared__ __align__(16) float xchg[2][2][4];       // [net][p&1][c]
  __shared__ float s1n[2][16][64], s2n[2][16][64];    // [net][tgt&15][ch]
  __shared__ int flg[8];  // 0+n:f0  2+n:f1  4+n:hf  6+n:xf

  for (int k = tid; k < 2*2*10*64; k += NT) {
    (&h0row[0][0][0][0])[k] = 0.f;
    (&h1row[0][0][0][0])[k] = 0.f;
  }
  for (int k = tid; k < 2*9*10*4; k += NT) (&yb[0][0][0][0])[k] = 0.f;
  for (int k = tid; k < 2*16*64; k += NT) {
    (&s1n[0][0][0])[k] = 0.f;
    (&s2n[0][0][0])[k] = 0.f;
  }
  if (tid < 8) flg[tid] = (tid < 4) ? -1 : (tid < 6 ? 7 : -1);

  __syncthreads();   // only barrier in the kernel

  volatile int* f0  = (volatile int*)&flg[0 + net];
  volatile int* f1  = (volatile int*)&flg[2 + net];
  volatile int* hf  = (volatile int*)&flg[4 + net];
  volatile int* xfo = (volatile int*)&flg[6 + net];
  volatile int* xfx = (volatile int*)&flg[6 + (1 - net)];

  if (role == 0) {
    // ================= S: full serial spine =================
    const float* w0g = net ? lw0 : mw0;
    const float* w1g = net ? lw1 : mw1;
    const float* w2g = net ? lw2 : mw2;
    const float* wog = net ? lwo : mwo;
    float w0t[16], wc1[64], w1w[64], wc2[64], w2w[64], wo4[4], xr[4];
    {
      const int KH[4] = {0,0,0,1};
      const int KW[4] = {0,1,2,0};
#pragma unroll
      for (int t4 = 0; t4 < 4; ++t4)
#pragma unroll
        for (int ic = 0; ic < 4; ++ic)
          w0t[t4*4+ic] = w0g[((ch*4 + ic)*3 + KH[t4])*3 + KW[t4]];
    }
#pragma unroll
    for (int q = 0; q < 64; ++q) {
      wc1[q] = w1g[((ch*64 + q)*3 + 1)*3 + 1];
      w1w[q] = w1g[((ch*64 + q)*3 + 1)*3 + 0];
      wc2[q] = w2g[((ch*64 + q)*3 + 1)*3 + 1];
      w2w[q] = w2g[((ch*64 + q)*3 + 1)*3 + 0];
    }
#pragma unroll
    for (int c = 0; c < 4; ++c) wo4[c] = wog[c*64 + ch];
#pragma unroll
    for (int c = 0; c < 4; ++c) xr[c] = x[b*256 + c*64 + ch];  // lane p: x[c][p]
    const float bA = (net ? lb0 : mb0)[ch];
    const float bB = (net ? lb1 : mb1)[ch];
    const float bC = (net ? lb2 : mb2)[ch];
    float boM[4], boL[4];
#pragma unroll
    for (int c = 0; c < 4; ++c) { boM[c] = mbo[c]; boL[c] = lbo[c]; }

    float os0 = 0.f, os1 = 0.f, os2 = 0.f, os3 = 0.f;  // own raw sums (p-1)
    float y0 = 0.f, y1 = 0.f, y2 = 0.f, y3 = 0.f;      // y(p-1)
    float lsacc = 0.f;

#pragma unroll 1
    for (int p = 0; p < 64; ++p) {
      const int i = p >> 3, j = p & 7, cur = i & 1, pb = p & 15;

      // ---- epi(p-1): own sums in regs, other net's via xchg ----
      if (p > 0) {
        const int pp = p - 1;
        poll_ge(xfx, pp);
        const float4 o4 = *reinterpret_cast<const float4*>(&xchg[1 - net][pp & 1][0]);
        const float m0 = net ? o4.x : os0, m1 = net ? o4.y : os1;
        const float m2 = net ? o4.z : os2, m3 = net ? o4.w : os3;
        const float l0 = net ? os0 : o4.x, l1 = net ? os1 : o4.y;
        const float l2 = net ? os2 : o4.z, l3 = net ? os3 : o4.w;
        y0 = (rdlane(xr[0], pp) - (m0 + boM[0])) / (expf(0.5f*(l0 + boL[0])) + 1e-12f);
        y1 = (rdlane(xr[1], pp) - (m1 + boM[1])) / (expf(0.5f*(l1 + boL[1])) + 1e-12f);
        y2 = (rdlane(xr[2], pp) - (m2 + boM[2])) / (expf(0.5f*(l2 + boL[2])) + 1e-12f);
        y3 = (rdlane(xr[3], pp) - (m3 + boM[3])) / (expf(0.5f*(l3 + boL[3])) + 1e-12f);
        if (ch == 0)
          *reinterpret_cast<float4*>(&yb[net][(pp>>3)+1][(pp&7)+1][0]) =
              make_float4(y0, y1, y2, y3);
      }

      // ---- h0(p): N-taps from yb, W-tap from y regs ----
      float acc = bA;
      {
        const float4 yNW = *reinterpret_cast<const float4*>(&yb[net][i][j    ][0]);
        const float4 yN  = *reinterpret_cast<const float4*>(&yb[net][i][j + 1][0]);
        const float4 yNE = *reinterpret_cast<const float4*>(&yb[net][i][j + 2][0]);
        acc += w0t[0]*yNW.x + w0t[1]*yNW.y + w0t[2]*yNW.z + w0t[3]*yNW.w;
        acc += w0t[4]*yN.x  + w0t[5]*yN.y  + w0t[6]*yN.z  + w0t[7]*yN.w;
        acc += w0t[8]*yNE.x + w0t[9]*yNE.y + w0t[10]*yNE.z + w0t[11]*yNE.w;
        if (j > 0) acc += w0t[12]*y0 + w0t[13]*y1 + w0t[14]*y2 + w0t[15]*y3;
      }
      const float h0v = elu(acc);
      h0row[net][cur][j + 1][ch] = h0v;
      set_flag(f0, p, ch == 0);

      // ---- W1: center via readlane on own h0v; West via DOTU on own
      //      last-pixel row write (pcol j; pad col 0 zeroes j==0) ----
      float c1;
      {
        float a0 = 0.f, a1 = 0.f, a2 = 0.f, a3 = 0.f;
#pragma unroll
        for (int q = 0; q < 16; ++q) {
          a0 += wc1[4*q+0] * rdlane(h0v, 4*q+0);
          a1 += wc1[4*q+1] * rdlane(h0v, 4*q+1);
          a2 += wc1[4*q+2] * rdlane(h0v, 4*q+2);
          a3 += wc1[4*q+3] * rdlane(h0v, 4*q+3);
        }
        c1 = (a0 + a1) + (a2 + a3);
      }
      float ww1;
      {
        float a0 = 0.f, a1 = 0.f, a2 = 0.f, a3 = 0.f;
        DOTU(w1w, &h0row[net][cur][j][0]);
        ww1 = (a0 + a1) + (a2 + a3);
      }

      poll_ge(hf, p);   // N-tap sums for p (>=7 px slack -> immediate)
      const float h1v = elu(((c1 + bB) + ww1) + s1n[net][pb][ch]);
      h1row[net][cur][j + 1][ch] = h1v;
      set_flag(f1, p, ch == 0);

      // ---- W2: center readlane on h1v; West DOTU ----
      float c2;
      {
        float a0 = 0.f, a1 = 0.f, a2 = 0.f, a3 = 0.f;
#pragma unroll
        for (int q = 0; q < 16; ++q) {
          a0 += wc2[4*q+0] * rdlane(h1v, 4*q+0);
          a1 += wc2[4*q+1] * rdlane(h1v, 4*q+1);
          a2 += wc2[4*q+2] * rdlane(h1v, 4*q+2);
          a3 += wc2[4*q+3] * rdlane(h1v, 4*q+3);
        }
        c2 = (a0 + a1) + (a2 + a3);
      }
      float ww2;
      {
        float a0 = 0.f, a1 = 0.f, a2 = 0.f, a3 = 0.f;
        DOTU(w2w, &h1row[net][cur][j][0]);
        ww2 = (a0 + a1) + (a2 + a3);
      }
      const float h2v = elu(((c2 + bC) + ww2) + s2n[net][pb][ch]);

      float s0 = wo4[0]*h2v, s1 = wo4[1]*h2v, s2 = wo4[2]*h2v, s3 = wo4[3]*h2v;
#pragma unroll
      for (int off = 32; off; off >>= 1) {
        s0 += __shfl_xor(s0, off, 64);
        s1 += __shfl_xor(s1, off, 64);
        s2 += __shfl_xor(s2, off, 64);
        s3 += __shfl_xor(s3, off, 64);
      }
      os0 = s0; os1 = s1; os2 = s2; os3 = s3;
      if (ch == 0)
        *reinterpret_cast<float4*>(&xchg[net][p & 1][0]) = make_float4(s0, s1, s2, s3);
      set_flag(xfo, p, ch == 0);
      if (net == 1)
        lsacc += 0.5f*((s0 + boL[0]) + (s1 + boL[1]) + (s2 + boL[2]) + (s3 + boL[3]));
    }

    // ---- final epi(63) + output ----
    poll_ge(xfx, 63);
    {
      const float4 o4 = *reinterpret_cast<const float4*>(&xchg[1 - net][1][0]);
      const float m0 = net ? o4.x : os0, m1 = net ? o4.y : os1;
      const float m2 = net ? o4.z : os2, m3 = net ? o4.w : os3;
      const float l0 = net ? os0 : o4.x, l1 = net ? os1 : o4.y;
      const float l2 = net ? os2 : o4.z, l3 = net ? os3 : o4.w;
      float fy0 = (rdlane(xr[0], 63) - (m0 + boM[0])) / (expf(0.5f*(l0 + boL[0])) + 1e-12f);
      float fy1 = (rdlane(xr[1], 63) - (m1 + boM[1])) / (expf(0.5f*(l1 + boL[1])) + 1e-12f);
      float fy2 = (rdlane(xr[2], 63) - (m2 + boM[2])) / (expf(0.5f*(l2 + boL[2])) + 1e-12f);
      float fy3 = (rdlane(xr[3], 63) - (m3 + boM[3])) / (expf(0.5f*(l3 + boL[3])) + 1e-12f);
      if (ch == 0)
        *reinterpret_cast<float4*>(&yb[net][8][8][0]) = make_float4(fy0, fy1, fy2, fy3);
    }
    if (net == 0) {
#pragma unroll
      for (int c = 0; c < 4; ++c)
        out[(b*4 + c)*64 + ch] = yb[0][(ch >> 3) + 1][(ch & 7) + 1][c];
    } else if (ch == 0) {
      out[32*4*64 + b] = lsacc;
    }

  } else {
    // ================= H: N-tap sums, >=7-px ahead of consumption =========
    const float* w1g = net ? lw1 : mw1;
    const float* w2g = net ? lw2 : mw2;
    float w1nw[64], w1n[64], w1ne[64], w2nw[64], w2n[64], w2ne[64];
#pragma unroll
    for (int q = 0; q < 64; ++q) {
      w1nw[q] = w1g[((ch*64 + q)*3 + 0)*3 + 0];
      w1n [q] = w1g[((ch*64 + q)*3 + 0)*3 + 1];
      w1ne[q] = w1g[((ch*64 + q)*3 + 0)*3 + 2];
      w2nw[q] = w2g[((ch*64 + q)*3 + 0)*3 + 0];
      w2n [q] = w2g[((ch*64 + q)*3 + 0)*3 + 1];
      w2ne[q] = w2g[((ch*64 + q)*3 + 0)*3 + 2];
    }
#pragma unroll 1
    for (int p2 = 8; p2 < 64; ++p2) {
      const int i2 = p2 >> 3, j2 = p2 & 7, sp = (i2 - 1) & 1;
      const int req = 8*(i2 - 1) + ((j2 < 7) ? j2 + 1 : 7);
      // spatial cols j2-1..j2+1 of row i2-1 -> pcols j2, j2+1, j2+2
      poll_ge(f0, req);
      {
        float a0 = 0.f, a1 = 0.f, a2 = 0.f, a3 = 0.f;
        DOTU(w1nw, &h0row[net][sp][j2    ][0]);
        DOTU(w1n,  &h0row[net][sp][j2 + 1][0]);
        DOTU(w1ne, &h0row[net][sp][j2 + 2][0]);
        s1n[net][p2 & 15][ch] = (a0 + a1) + (a2 + a3);
      }
      poll_ge(f1, req);
      {
        float a0 = 0.f, a1 = 0.f, a2 = 0.f, a3 = 0.f;
        DOTU(w2nw, &h1row[net][sp][j2    ][0]);
        DOTU(w2n,  &h1row[net][sp][j2 + 1][0]);
        DOTU(w2ne, &h1row[net][sp][j2 + 2][0]);
        s2n[net][p2 & 15][ch] = (a0 + a1) + (a2 + a3);
      }
      set_flag(hf, p2, ch == 0);
    }
  }
}

extern "C" void kernel_launch(void* const* d_in, const int* in_sizes, int n_in,
                              void* d_out, int out_size, void* d_ws, size_t ws_size,
                              hipStream_t stream) {
  (void)in_sizes; (void)n_in; (void)out_size; (void)d_ws; (void)ws_size;
  made_ar_decode_k<<<dim3(32), dim3(NT), 0, stream>>>(
      (const float*)d_in[0],
      (const float*)d_in[1],  (const float*)d_in[2],
      (const float*)d_in[3],  (const float*)d_in[4],
      (const float*)d_in[5],  (const float*)d_in[6],
      (const float*)d_in[7],  (const float*)d_in[8],
      (const float*)d_in[9],  (const float*)d_in[10],
      (const float*)d_in[11], (const float*)d_in[12],
      (const float*)d_in[13], (const float*)d_in[14],
      (const float*)d_in[15], (const float*)d_in[16],
      (float*)d_out);
}

// Round 18
// 217.050 us; speedup vs baseline: 1.2262x; 1.2262x over previous
//
#include <hip/hip_runtime.h>

// MADE / PixelCNN autoregressive inverse (all fp32, per reference).
//
// FINAL STRUCTURE (r11, session best: 137.8us rocprof / 219.8us harness)
// + spine s_setprio(1) (role-diverse waves -> priority has something to
// arbitrate, unlike lockstep GEMM where it nulls).
//
// Design-space sweep (18 rounds): sync {6-bar, 2-bar, spin-flags x3},
// split {16/12/8/4/2 waves}, MAC {readlane, LDS-broadcast, reg}, slots
// {64 raster, 22 anti-diagonal}, regs {pins, no-pins, AGPR}: every
// alternative regressed. Invariant: ~2.15us per serial decode step,
// insensitive to slot contents -> floor = rendezvous + LDS visibility +
// dependent-chain latency per step, not issue. r11's 2-barrier/8-wave
// balanced schedule minimizes it:
//  * W1 off-center taps for p+1 need only h0(<=p) -> computed in helpers'
//    POST-B1 phase (overlapping spine's h1->c2->h2->butterfly); pre-B1
//    keeps only W2 dots (need h1(p-1)).
//  * W1 partials parity-double-buffered (write slot p, read post-B1 of
//    p+1); W2 partials single-buffered (write pre-B1, read post-B1).
// Roles per net: S (spine: epi,h0,c1 | h1,c2,h2,butterfly,xchg),
//  Ha: pre {W2NW,W2N} / post {W1NW};  Hb: pre {W2NE} / post {W1N,W1NE};
//  Hc: pre {W2W}     / post {W1W}.
// LDS pad cols 0/9 never written -> zero taps at borders for free.

#define NT 512

__device__ __forceinline__ float elu(float x) { return x > 0.f ? x : expm1f(x); }

__device__ __forceinline__ float rdlane(float v, int l) {
  return __int_as_float(__builtin_amdgcn_readlane(__float_as_int(v), l));
}

#define BAR() asm volatile("s_waitcnt lgkmcnt(0)\n\ts_barrier" ::: "memory")

// one 64-dot quarter-step: acc{0..3} += W_[4q+m] * (lane-q broadcast of F_ members)
#define DOT16(W_, F_)                                                \
  _Pragma("unroll")                                                  \
  for (int q = 0; q < 16; ++q) {                                     \
    a0 += (W_)[4*q+0] * rdlane((F_).x, q);                           \
    a1 += (W_)[4*q+1] * rdlane((F_).y, q);                           \
    a2 += (W_)[4*q+2] * rdlane((F_).z, q);                           \
    a3 += (W_)[4*q+3] * rdlane((F_).w, q);                           \
  }

#define FRAG(P_) (reinterpret_cast<const float4*>(P_)[ch & 15])

__global__ __launch_bounds__(NT)
__attribute__((amdgpu_waves_per_eu(2, 2)))
void made_ar_decode_k(
    const float* __restrict__ x,
    const float* __restrict__ mw0, const float* __restrict__ mb0,
    const float* __restrict__ mw1, const float* __restrict__ mb1,
    const float* __restrict__ mw2, const float* __restrict__ mb2,
    const float* __restrict__ mwo, const float* __restrict__ mbo,
    const float* __restrict__ lw0, const float* __restrict__ lb0,
    const float* __restrict__ lw1, const float* __restrict__ lb1,
    const float* __restrict__ lw2, const float* __restrict__ lb2,
    const float* __restrict__ lwo, const float* __restrict__ lbo,
    float* __restrict__ out)
{
  const int b    = blockIdx.x;
  const int tid  = threadIdx.x;
  const int wv   = tid >> 6;       // 0..7
  const int net  = wv & 1;         // 0 = mu, 1 = lv
  const int role = wv >> 1;        // 0:S  1:Hb  2:Ha  3:Hc
  const int ch   = tid & 63;       // lane == out channel

  // parity double-buffered row caches; pcol = spatial col + 1; pad cols 0,9
  // never written -> permanent zeros ('SAME' border).
  __shared__ __align__(16) float h0row[2][2][10][64]; // [net][par][pcol][ch]
  __shared__ __align__(16) float h1row[2][2][10][64];
  __shared__ __align__(16) float yb[2][9][10][4];     // [net][prow][pcol][c]
  __shared__ __align__(16) float xchg[2][2][4];       // [p&1][net][c]
  __shared__ float r1a[2][2][64], r1b[2][2][64], r1c[2][2][64]; // [pix&1][net][ch] W1 partials
  __shared__ float r2a[2][64], r2b[2][64], r2c[2][64];          // [net][ch] W2 partials
  __shared__ float xls[256];

  for (int k = tid; k < 2*2*10*64; k += NT) {
    (&h0row[0][0][0][0])[k] = 0.f;
    (&h1row[0][0][0][0])[k] = 0.f;
  }
  for (int k = tid; k < 2*9*10*4; k += NT) (&yb[0][0][0][0])[k] = 0.f;
  for (int k = tid; k < 2*2*64; k += NT) {
    (&r1a[0][0][0])[k] = 0.f;
    (&r1b[0][0][0])[k] = 0.f;
    (&r1c[0][0][0])[k] = 0.f;
  }
  if (tid < 256) xls[tid] = x[b*256 + tid];   // [c][i][j] flat = c*64 + p

  __syncthreads();   // uniform join after init

  if (role == 0) {
    // ================= S: serial spine =================
    __builtin_amdgcn_s_setprio(1);   // critical-path wave; helpers have slack
    const float* w0g = net ? lw0 : mw0;
    const float* w1g = net ? lw1 : mw1;
    const float* w2g = net ? lw2 : mw2;
    const float* wog = net ? lwo : mwo;
    const int KH[4] = {0,0,0,1};
    const int KW[4] = {0,1,2,0};
    float waux[16], wc1[64], wc2[64], wo4[4];
#pragma unroll
    for (int t = 0; t < 4; ++t)
#pragma unroll
      for (int ic = 0; ic < 4; ++ic)
        waux[t*4 + ic] = w0g[((ch*4 + ic)*3 + KH[t])*3 + KW[t]];
#pragma unroll
    for (int q = 0; q < 64; ++q) wc1[q] = w1g[((ch*64 + q)*3 + 1)*3 + 1];
#pragma unroll
    for (int q = 0; q < 64; ++q) wc2[q] = w2g[((ch*64 + q)*3 + 1)*3 + 1];
#pragma unroll
    for (int c = 0; c < 4; ++c) wo4[c] = wog[c*64 + ch];
    const float bA = (net ? lb0 : mb0)[ch];
    const float bB = (net ? lb1 : mb1)[ch];
    const float bC = (net ? lb2 : mb2)[ch];
    float boM[4], boL[4];
#pragma unroll
    for (int c = 0; c < 4; ++c) { boM[c] = mbo[c]; boL[c] = lbo[c]; }

    float lsacc = 0.f;

#pragma unroll 1
    for (int p = 0; p < 64; ++p) {
      const int i = p >> 3, j = p & 7, cur = i & 1, pb = p & 1;

      // ---- pre-B1: epi(p-1), h0(p), c1 ----
      if (p > 0) {
        const int pp = p - 1;
        const float4 m4 = *reinterpret_cast<const float4*>(&xchg[pp & 1][0][0]);
        const float4 l4 = *reinterpret_cast<const float4*>(&xchg[pp & 1][1][0]);
        float y0 = (xls[0*64+pp] - (m4.x + boM[0])) / (expf(0.5f*(l4.x + boL[0])) + 1e-12f);
        float y1 = (xls[1*64+pp] - (m4.y + boM[1])) / (expf(0.5f*(l4.y + boL[1])) + 1e-12f);
        float y2 = (xls[2*64+pp] - (m4.z + boM[2])) / (expf(0.5f*(l4.z + boL[2])) + 1e-12f);
        float y3 = (xls[3*64+pp] - (m4.w + boM[3])) / (expf(0.5f*(l4.w + boL[3])) + 1e-12f);
        if (ch == 0)
          *reinterpret_cast<float4*>(&yb[net][(pp>>3)+1][(pp&7)+1][0]) =
              make_float4(y0, y1, y2, y3);
      }
      float acc = bA;
#pragma unroll
      for (int t = 0; t < 4; ++t) {
        const float4 yv = *reinterpret_cast<const float4*>(&yb[net][i + KH[t]][j + KW[t]][0]);
        acc += waux[t*4+0]*yv.x + waux[t*4+1]*yv.y
             + waux[t*4+2]*yv.z + waux[t*4+3]*yv.w;
      }
      const float h0v = elu(acc);
      h0row[net][cur][j + 1][ch] = h0v;

      float c1;
      {
        float a0 = 0.f, a1 = 0.f, a2 = 0.f, a3 = 0.f;
#pragma unroll
        for (int q = 0; q < 16; ++q) {
          a0 += wc1[4*q+0] * rdlane(h0v, 4*q+0);
          a1 += wc1[4*q+1] * rdlane(h0v, 4*q+1);
          a2 += wc1[4*q+2] * rdlane(h0v, 4*q+2);
          a3 += wc1[4*q+3] * rdlane(h0v, 4*q+3);
        }
        c1 = (a0 + a1) + (a2 + a3);
      }

      BAR();   // B1: h0(p), c-partials visible

      // ---- post-B1: h1, c2, h2, out-conv ----
      const float h1v = elu(((c1 + bB) + (r1a[pb][net][ch] + r1b[pb][net][ch]))
                            + r1c[pb][net][ch]);
      h1row[net][cur][j + 1][ch] = h1v;

      float c2;
      {
        float a0 = 0.f, a1 = 0.f, a2 = 0.f, a3 = 0.f;
#pragma unroll
        for (int q = 0; q < 16; ++q) {
          a0 += wc2[4*q+0] * rdlane(h1v, 4*q+0);
          a1 += wc2[4*q+1] * rdlane(h1v, 4*q+1);
          a2 += wc2[4*q+2] * rdlane(h1v, 4*q+2);
          a3 += wc2[4*q+3] * rdlane(h1v, 4*q+3);
        }
        c2 = (a0 + a1) + (a2 + a3);
      }
      const float h2v = elu(((c2 + bC) + (r2a[net][ch] + r2b[net][ch]))
                            + r2c[net][ch]);

      float s0 = wo4[0]*h2v, s1 = wo4[1]*h2v, s2 = wo4[2]*h2v, s3 = wo4[3]*h2v;
#pragma unroll
      for (int off = 32; off; off >>= 1) {
        s0 += __shfl_xor(s0, off, 64);
        s1 += __shfl_xor(s1, off, 64);
        s2 += __shfl_xor(s2, off, 64);
        s3 += __shfl_xor(s3, off, 64);
      }
      if (ch == 0)
        *reinterpret_cast<float4*>(&xchg[p & 1][net][0]) = make_float4(s0, s1, s2, s3);
      if (net == 1 && ch == 0)
        lsacc += 0.5f*((s0 + boL[0]) + (s1 + boL[1]) + (s2 + boL[2]) + (s3 + boL[3]));

      BAR();   // B2
    }

    // final y(63) into yb (for the copy-out)
    {
      const float4 m4 = *reinterpret_cast<const float4*>(&xchg[1][0][0]);
      const float4 l4 = *reinterpret_cast<const float4*>(&xchg[1][1][0]);
      float y0 = (xls[0*64+63] - (m4.x + boM[0])) / (expf(0.5f*(l4.x + boL[0])) + 1e-12f);
      float y1 = (xls[1*64+63] - (m4.y + boM[1])) / (expf(0.5f*(l4.y + boL[1])) + 1e-12f);
      float y2 = (xls[2*64+63] - (m4.z + boM[2])) / (expf(0.5f*(l4.z + boL[2])) + 1e-12f);
      float y3 = (xls[3*64+63] - (m4.w + boM[3])) / (expf(0.5f*(l4.w + boL[3])) + 1e-12f);
      if (ch == 0)
        *reinterpret_cast<float4*>(&yb[net][8][8][0]) = make_float4(y0, y1, y2, y3);
    }
    if (net == 1 && ch == 0) out[32*4*64 + b] = lsacc;
    __builtin_amdgcn_s_setprio(0);

  } else if (role == 1) {
    // ===== Hb: pre {W2 NE} ; post {W1 N, W1 NE (for p+1)} =====
    const float* w1g = net ? lw1 : mw1;
    const float* w2g = net ? lw2 : mw2;
    float w2ne[64], w1n[64], w1ne[64];
#pragma unroll
    for (int q = 0; q < 64; ++q) {
      w2ne[q] = w2g[((ch*64 + q)*3 + 0)*3 + 2];
      w1n [q] = w1g[((ch*64 + q)*3 + 0)*3 + 1];
      w1ne[q] = w1g[((ch*64 + q)*3 + 0)*3 + 2];
    }
#pragma unroll 1
    for (int p = 0; p < 64; ++p) {
      const int i = p >> 3, j = p & 7, cur = i & 1, prv = cur ^ 1;
      {
        const float4 f = FRAG(&h1row[net][prv][j + 2][0]);
        float a0 = 0.f, a1 = 0.f, a2 = 0.f, a3 = 0.f;
        DOT16(w2ne, f);
        r2b[net][ch] = (a0 + a1) + (a2 + a3);
      }
      BAR();
      if (p < 63) {
        const int p2 = p + 1, i2 = p2 >> 3, j2 = p2 & 7;
        float v = 0.f;
        if (i2 >= 1) {
          const int sp = (i2 - 1) & 1;
          const float4 fN  = FRAG(&h0row[net][sp][j2 + 1][0]);
          const float4 fNE = FRAG(&h0row[net][sp][j2 + 2][0]);
          float a0 = 0.f, a1 = 0.f, a2 = 0.f, a3 = 0.f;
          DOT16(w1n,  fN);
          DOT16(w1ne, fNE);
          v = (a0 + a1) + (a2 + a3);
        }
        r1b[p2 & 1][net][ch] = v;
      }
      BAR();
    }

  } else if (role == 2) {
    // ===== Ha: pre {W2 NW, W2 N} ; post {W1 NW (for p+1)} =====
    const float* w1g = net ? lw1 : mw1;
    const float* w2g = net ? lw2 : mw2;
    float w2nw[64], w2n[64], w1nw[64];
#pragma unroll
    for (int q = 0; q < 64; ++q) {
      w2nw[q] = w2g[((ch*64 + q)*3 + 0)*3 + 0];
      w2n [q] = w2g[((ch*64 + q)*3 + 0)*3 + 1];
      w1nw[q] = w1g[((ch*64 + q)*3 + 0)*3 + 0];
    }
#pragma unroll 1
    for (int p = 0; p < 64; ++p) {
      const int i = p >> 3, j = p & 7, cur = i & 1, prv = cur ^ 1;
      {
        const float4 fNW = FRAG(&h1row[net][prv][j    ][0]);
        const float4 fN  = FRAG(&h1row[net][prv][j + 1][0]);
        float a0 = 0.f, a1 = 0.f, a2 = 0.f, a3 = 0.f;
        DOT16(w2nw, fNW);
        DOT16(w2n,  fN);
        r2a[net][ch] = (a0 + a1) + (a2 + a3);
      }
      BAR();
      if (p < 63) {
        const int p2 = p + 1, i2 = p2 >> 3, j2 = p2 & 7;
        float v = 0.f;
        if (i2 >= 1) {
          const int sp = (i2 - 1) & 1;
          const float4 f = FRAG(&h0row[net][sp][j2][0]);
          float a0 = 0.f, a1 = 0.f, a2 = 0.f, a3 = 0.f;
          DOT16(w1nw, f);
          v = (a0 + a1) + (a2 + a3);
        }
        r1a[p2 & 1][net][ch] = v;
      }
      BAR();
    }

  } else {
    // ===== Hc: pre {W2 W vs h1(p-1)} ; post {W1 W vs h0(p) (for p+1)} =====
    const float* w1g = net ? lw1 : mw1;
    const float* w2g = net ? lw2 : mw2;
    float w2w[64], w1w[64];
#pragma unroll
    for (int q = 0; q < 64; ++q) {
      w2w[q] = w2g[((ch*64 + q)*3 + 1)*3 + 0];
      w1w[q] = w1g[((ch*64 + q)*3 + 1)*3 + 0];
    }
#pragma unroll 1
    for (int p = 0; p < 64; ++p) {
      const int i = p >> 3, j = p & 7, cur = i & 1;
      {
        // pcol j: pad col 0 gives zero at j==0 automatically
        const float4 f = FRAG(&h1row[net][cur][j][0]);
        float a0 = 0.f, a1 = 0.f, a2 = 0.f, a3 = 0.f;
        DOT16(w2w, f);
        r2c[net][ch] = (a0 + a1) + (a2 + a3);
      }
      BAR();
      if (p < 63) {
        const int p2 = p + 1, j2 = p2 & 7;
        float v = 0.f;
        if (j2 > 0) {   // same row: W tap = h0(p), just written pre-B1
          const float4 f = FRAG(&h0row[net][cur][j + 1][0]);
          float a0 = 0.f, a1 = 0.f, a2 = 0.f, a3 = 0.f;
          DOT16(w1w, f);
          v = (a0 + a1) + (a2 + a3);
        }
        r1c[p2 & 1][net][ch] = v;
      }
      BAR();
    }
  }

  BAR();   // join: yb complete (incl. y(63))

  // copy-out: y from net-0's yb
  if (tid < 256) {
    const int c = tid >> 6, p = tid & 63;
    out[(b*4 + c)*64 + p] = yb[0][(p >> 3) + 1][(p & 7) + 1][c];
  }
}

extern "C" void kernel_launch(void* const* d_in, const int* in_sizes, int n_in,
                              void* d_out, int out_size, void* d_ws, size_t ws_size,
                              hipStream_t stream) {
  (void)in_sizes; (void)n_in; (void)out_size; (void)d_ws; (void)ws_size;
  made_ar_decode_k<<<dim3(32), dim3(NT), 0, stream>>>(
      (const float*)d_in[0],
      (const float*)d_in[1],  (const float*)d_in[2],
      (const float*)d_in[3],  (const float*)d_in[4],
      (const float*)d_in[5],  (const float*)d_in[6],
      (const float*)d_in[7],  (const float*)d_in[8],
      (const float*)d_in[9],  (const float*)d_in[10],
      (const float*)d_in[11], (const float*)d_in[12],
      (const float*)d_in[13], (const float*)d_in[14],
      (const float*)d_in[15], (const float*)d_in[16],
      (float*)d_out);
}

// Round 19
// 211.275 us; speedup vs baseline: 1.2597x; 1.0273x over previous
//
#include <hip/hip_runtime.h>

// MADE / PixelCNN autoregressive inverse (all fp32, per reference).
//
// FINAL STRUCTURE (r11/r18, session best: 136.7us rocprof / 217.0us
// harness) + r19: epilogue divide removed from the serial critical path --
// y = (x-mu)*__expf(-ls) instead of (x-mu)/(expf(ls)+1e-12). The eps guard
// only matters for ls < -20 (actual ls is O(1)); rounding diff ~1e-7 rel,
// threshold 8.9e-2. Saves 4 full-precision div sequences (~150-300 cy of
// chain latency) per pixel.
//
// Design-space sweep (19 rounds): sync {6-bar, 2-bar, spin-flags x3},
// split {16/12/8/4/2 waves}, MAC {readlane, LDS-broadcast, reg}, slots
// {64 raster, 22 anti-diagonal}, regs {pins, no-pins, AGPR}: every
// alternative regressed. Invariant: ~2.15us per serial decode step,
// insensitive to slot contents -> floor = rendezvous + LDS visibility +
// dependent-chain latency per step, not issue. r11's 2-barrier/8-wave
// balanced schedule minimizes it:
//  * W1 off-center taps for p+1 need only h0(<=p) -> computed in helpers'
//    POST-B1 phase (overlapping spine's h1->c2->h2->butterfly); pre-B1
//    keeps only W2 dots (need h1(p-1)).
//  * W1 partials parity-double-buffered (write slot p, read post-B1 of
//    p+1); W2 partials single-buffered (write pre-B1, read post-B1).
// Roles per net: S (spine: epi,h0,c1 | h1,c2,h2,butterfly,xchg),
//  Ha: pre {W2NW,W2N} / post {W1NW};  Hb: pre {W2NE} / post {W1N,W1NE};
//  Hc: pre {W2W}     / post {W1W}.
// LDS pad cols 0/9 never written -> zero taps at borders for free.

#define NT 512

__device__ __forceinline__ float elu(float x) { return x > 0.f ? x : expm1f(x); }

__device__ __forceinline__ float rdlane(float v, int l) {
  return __int_as_float(__builtin_amdgcn_readlane(__float_as_int(v), l));
}

#define BAR() asm volatile("s_waitcnt lgkmcnt(0)\n\ts_barrier" ::: "memory")

// one 64-dot quarter-step: acc{0..3} += W_[4q+m] * (lane-q broadcast of F_ members)
#define DOT16(W_, F_)                                                \
  _Pragma("unroll")                                                  \
  for (int q = 0; q < 16; ++q) {                                     \
    a0 += (W_)[4*q+0] * rdlane((F_).x, q);                           \
    a1 += (W_)[4*q+1] * rdlane((F_).y, q);                           \
    a2 += (W_)[4*q+2] * rdlane((F_).z, q);                           \
    a3 += (W_)[4*q+3] * rdlane((F_).w, q);                           \
  }

#define FRAG(P_) (reinterpret_cast<const float4*>(P_)[ch & 15])

__global__ __launch_bounds__(NT)
__attribute__((amdgpu_waves_per_eu(2, 2)))
void made_ar_decode_k(
    const float* __restrict__ x,
    const float* __restrict__ mw0, const float* __restrict__ mb0,
    const float* __restrict__ mw1, const float* __restrict__ mb1,
    const float* __restrict__ mw2, const float* __restrict__ mb2,
    const float* __restrict__ mwo, const float* __restrict__ mbo,
    const float* __restrict__ lw0, const float* __restrict__ lb0,
    const float* __restrict__ lw1, const float* __restrict__ lb1,
    const float* __restrict__ lw2, const float* __restrict__ lb2,
    const float* __restrict__ lwo, const float* __restrict__ lbo,
    float* __restrict__ out)
{
  const int b    = blockIdx.x;
  const int tid  = threadIdx.x;
  const int wv   = tid >> 6;       // 0..7
  const int net  = wv & 1;         // 0 = mu, 1 = lv
  const int role = wv >> 1;        // 0:S  1:Hb  2:Ha  3:Hc
  const int ch   = tid & 63;       // lane == out channel

  // parity double-buffered row caches; pcol = spatial col + 1; pad cols 0,9
  // never written -> permanent zeros ('SAME' border).
  __shared__ __align__(16) float h0row[2][2][10][64]; // [net][par][pcol][ch]
  __shared__ __align__(16) float h1row[2][2][10][64];
  __shared__ __align__(16) float yb[2][9][10][4];     // [net][prow][pcol][c]
  __shared__ __align__(16) float xchg[2][2][4];       // [p&1][net][c]
  __shared__ float r1a[2][2][64], r1b[2][2][64], r1c[2][2][64]; // [pix&1][net][ch] W1 partials
  __shared__ float r2a[2][64], r2b[2][64], r2c[2][64];          // [net][ch] W2 partials
  __shared__ float xls[256];

  for (int k = tid; k < 2*2*10*64; k += NT) {
    (&h0row[0][0][0][0])[k] = 0.f;
    (&h1row[0][0][0][0])[k] = 0.f;
  }
  for (int k = tid; k < 2*9*10*4; k += NT) (&yb[0][0][0][0])[k] = 0.f;
  for (int k = tid; k < 2*2*64; k += NT) {
    (&r1a[0][0][0])[k] = 0.f;
    (&r1b[0][0][0])[k] = 0.f;
    (&r1c[0][0][0])[k] = 0.f;
  }
  if (tid < 256) xls[tid] = x[b*256 + tid];   // [c][i][j] flat = c*64 + p

  __syncthreads();   // uniform join after init

  if (role == 0) {
    // ================= S: serial spine =================
    __builtin_amdgcn_s_setprio(1);   // critical-path wave; helpers have slack
    const float* w0g = net ? lw0 : mw0;
    const float* w1g = net ? lw1 : mw1;
    const float* w2g = net ? lw2 : mw2;
    const float* wog = net ? lwo : mwo;
    const int KH[4] = {0,0,0,1};
    const int KW[4] = {0,1,2,0};
    float waux[16], wc1[64], wc2[64], wo4[4];
#pragma unroll
    for (int t = 0; t < 4; ++t)
#pragma unroll
      for (int ic = 0; ic < 4; ++ic)
        waux[t*4 + ic] = w0g[((ch*4 + ic)*3 + KH[t])*3 + KW[t]];
#pragma unroll
    for (int q = 0; q < 64; ++q) wc1[q] = w1g[((ch*64 + q)*3 + 1)*3 + 1];
#pragma unroll
    for (int q = 0; q < 64; ++q) wc2[q] = w2g[((ch*64 + q)*3 + 1)*3 + 1];
#pragma unroll
    for (int c = 0; c < 4; ++c) wo4[c] = wog[c*64 + ch];
    const float bA = (net ? lb0 : mb0)[ch];
    const float bB = (net ? lb1 : mb1)[ch];
    const float bC = (net ? lb2 : mb2)[ch];
    float boM[4], boL[4];
#pragma unroll
    for (int c = 0; c < 4; ++c) { boM[c] = mbo[c]; boL[c] = lbo[c]; }

    float lsacc = 0.f;

#pragma unroll 1
    for (int p = 0; p < 64; ++p) {
      const int i = p >> 3, j = p & 7, cur = i & 1, pb = p & 1;

      // ---- pre-B1: epi(p-1), h0(p), c1 ----
      if (p > 0) {
        const int pp = p - 1;
        const float4 m4 = *reinterpret_cast<const float4*>(&xchg[pp & 1][0][0]);
        const float4 l4 = *reinterpret_cast<const float4*>(&xchg[pp & 1][1][0]);
        // y = (x-mu)*exp(-ls): the 1e-12 guard only matters for ls < -20
        // (actual ls is O(1)); saves 4 serialized fp32 div sequences/px.
        float y0 = (xls[0*64+pp] - (m4.x + boM[0])) * __expf(-0.5f*(l4.x + boL[0]));
        float y1 = (xls[1*64+pp] - (m4.y + boM[1])) * __expf(-0.5f*(l4.y + boL[1]));
        float y2 = (xls[2*64+pp] - (m4.z + boM[2])) * __expf(-0.5f*(l4.z + boL[2]));
        float y3 = (xls[3*64+pp] - (m4.w + boM[3])) * __expf(-0.5f*(l4.w + boL[3]));
        if (ch == 0)
          *reinterpret_cast<float4*>(&yb[net][(pp>>3)+1][(pp&7)+1][0]) =
              make_float4(y0, y1, y2, y3);
      }
      float acc = bA;
#pragma unroll
      for (int t = 0; t < 4; ++t) {
        const float4 yv = *reinterpret_cast<const float4*>(&yb[net][i + KH[t]][j + KW[t]][0]);
        acc += waux[t*4+0]*yv.x + waux[t*4+1]*yv.y
             + waux[t*4+2]*yv.z + waux[t*4+3]*yv.w;
      }
      const float h0v = elu(acc);
      h0row[net][cur][j + 1][ch] = h0v;

      float c1;
      {
        float a0 = 0.f, a1 = 0.f, a2 = 0.f, a3 = 0.f;
#pragma unroll
        for (int q = 0; q < 16; ++q) {
          a0 += wc1[4*q+0] * rdlane(h0v, 4*q+0);
          a1 += wc1[4*q+1] * rdlane(h0v, 4*q+1);
          a2 += wc1[4*q+2] * rdlane(h0v, 4*q+2);
          a3 += wc1[4*q+3] * rdlane(h0v, 4*q+3);
        }
        c1 = (a0 + a1) + (a2 + a3);
      }

      BAR();   // B1: h0(p), c-partials visible

      // ---- post-B1: h1, c2, h2, out-conv ----
      const float h1v = elu(((c1 + bB) + (r1a[pb][net][ch] + r1b[pb][net][ch]))
                            + r1c[pb][net][ch]);
      h1row[net][cur][j + 1][ch] = h1v;

      float c2;
      {
        float a0 = 0.f, a1 = 0.f, a2 = 0.f, a3 = 0.f;
#pragma unroll
        for (int q = 0; q < 16; ++q) {
          a0 += wc2[4*q+0] * rdlane(h1v, 4*q+0);
          a1 += wc2[4*q+1] * rdlane(h1v, 4*q+1);
          a2 += wc2[4*q+2] * rdlane(h1v, 4*q+2);
          a3 += wc2[4*q+3] * rdlane(h1v, 4*q+3);
        }
        c2 = (a0 + a1) + (a2 + a3);
      }
      const float h2v = elu(((c2 + bC) + (r2a[net][ch] + r2b[net][ch]))
                            + r2c[net][ch]);

      float s0 = wo4[0]*h2v, s1 = wo4[1]*h2v, s2 = wo4[2]*h2v, s3 = wo4[3]*h2v;
#pragma unroll
      for (int off = 32; off; off >>= 1) {
        s0 += __shfl_xor(s0, off, 64);
        s1 += __shfl_xor(s1, off, 64);
        s2 += __shfl_xor(s2, off, 64);
        s3 += __shfl_xor(s3, off, 64);
      }
      if (ch == 0)
        *reinterpret_cast<float4*>(&xchg[p & 1][net][0]) = make_float4(s0, s1, s2, s3);
      if (net == 1 && ch == 0)
        lsacc += 0.5f*((s0 + boL[0]) + (s1 + boL[1]) + (s2 + boL[2]) + (s3 + boL[3]));

      BAR();   // B2
    }

    // final y(63) into yb (for the copy-out)
    {
      const float4 m4 = *reinterpret_cast<const float4*>(&xchg[1][0][0]);
      const float4 l4 = *reinterpret_cast<const float4*>(&xchg[1][1][0]);
      float y0 = (xls[0*64+63] - (m4.x + boM[0])) * __expf(-0.5f*(l4.x + boL[0]));
      float y1 = (xls[1*64+63] - (m4.y + boM[1])) * __expf(-0.5f*(l4.y + boL[1]));
      float y2 = (xls[2*64+63] - (m4.z + boM[2])) * __expf(-0.5f*(l4.z + boL[2]));
      float y3 = (xls[3*64+63] - (m4.w + boM[3])) * __expf(-0.5f*(l4.w + boL[3]));
      if (ch == 0)
        *reinterpret_cast<float4*>(&yb[net][8][8][0]) = make_float4(y0, y1, y2, y3);
    }
    if (net == 1 && ch == 0) out[32*4*64 + b] = lsacc;
    __builtin_amdgcn_s_setprio(0);

  } else if (role == 1) {
    // ===== Hb: pre {W2 NE} ; post {W1 N, W1 NE (for p+1)} =====
    const float* w1g = net ? lw1 : mw1;
    const float* w2g = net ? lw2 : mw2;
    float w2ne[64], w1n[64], w1ne[64];
#pragma unroll
    for (int q = 0; q < 64; ++q) {
      w2ne[q] = w2g[((ch*64 + q)*3 + 0)*3 + 2];
      w1n [q] = w1g[((ch*64 + q)*3 + 0)*3 + 1];
      w1ne[q] = w1g[((ch*64 + q)*3 + 0)*3 + 2];
    }
#pragma unroll 1
    for (int p = 0; p < 64; ++p) {
      const int i = p >> 3, j = p & 7, cur = i & 1, prv = cur ^ 1;
      {
        const float4 f = FRAG(&h1row[net][prv][j + 2][0]);
        float a0 = 0.f, a1 = 0.f, a2 = 0.f, a3 = 0.f;
        DOT16(w2ne, f);
        r2b[net][ch] = (a0 + a1) + (a2 + a3);
      }
      BAR();
      if (p < 63) {
        const int p2 = p + 1, i2 = p2 >> 3, j2 = p2 & 7;
        float v = 0.f;
        if (i2 >= 1) {
          const int sp = (i2 - 1) & 1;
          const float4 fN  = FRAG(&h0row[net][sp][j2 + 1][0]);
          const float4 fNE = FRAG(&h0row[net][sp][j2 + 2][0]);
          float a0 = 0.f, a1 = 0.f, a2 = 0.f, a3 = 0.f;
          DOT16(w1n,  fN);
          DOT16(w1ne, fNE);
          v = (a0 + a1) + (a2 + a3);
        }
        r1b[p2 & 1][net][ch] = v;
      }
      BAR();
    }

  } else if (role == 2) {
    // ===== Ha: pre {W2 NW, W2 N} ; post {W1 NW (for p+1)} =====
    const float* w1g = net ? lw1 : mw1;
    const float* w2g = net ? lw2 : mw2;
    float w2nw[64], w2n[64], w1nw[64];
#pragma unroll
    for (int q = 0; q < 64; ++q) {
      w2nw[q] = w2g[((ch*64 + q)*3 + 0)*3 + 0];
      w2n [q] = w2g[((ch*64 + q)*3 + 0)*3 + 1];
      w1nw[q] = w1g[((ch*64 + q)*3 + 0)*3 + 0];
    }
#pragma unroll 1
    for (int p = 0; p < 64; ++p) {
      const int i = p >> 3, j = p & 7, cur = i & 1, prv = cur ^ 1;
      {
        const float4 fNW = FRAG(&h1row[net][prv][j    ][0]);
        const float4 fN  = FRAG(&h1row[net][prv][j + 1][0]);
        float a0 = 0.f, a1 = 0.f, a2 = 0.f, a3 = 0.f;
        DOT16(w2nw, fNW);
        DOT16(w2n,  fN);
        r2a[net][ch] = (a0 + a1) + (a2 + a3);
      }
      BAR();
      if (p < 63) {
        const int p2 = p + 1, i2 = p2 >> 3, j2 = p2 & 7;
        float v = 0.f;
        if (i2 >= 1) {
          const int sp = (i2 - 1) & 1;
          const float4 f = FRAG(&h0row[net][sp][j2][0]);
          float a0 = 0.f, a1 = 0.f, a2 = 0.f, a3 = 0.f;
          DOT16(w1nw, f);
          v = (a0 + a1) + (a2 + a3);
        }
        r1a[p2 & 1][net][ch] = v;
      }
      BAR();
    }

  } else {
    // ===== Hc: pre {W2 W vs h1(p-1)} ; post {W1 W vs h0(p) (for p+1)} =====
    const float* w1g = net ? lw1 : mw1;
    const float* w2g = net ? lw2 : mw2;
    float w2w[64], w1w[64];
#pragma unroll
    for (int q = 0; q < 64; ++q) {
      w2w[q] = w2g[((ch*64 + q)*3 + 1)*3 + 0];
      w1w[q] = w1g[((ch*64 + q)*3 + 1)*3 + 0];
    }
#pragma unroll 1
    for (int p = 0; p < 64; ++p) {
      const int i = p >> 3, j = p & 7, cur = i & 1;
      {
        // pcol j: pad col 0 gives zero at j==0 automatically
        const float4 f = FRAG(&h1row[net][cur][j][0]);
        float a0 = 0.f, a1 = 0.f, a2 = 0.f, a3 = 0.f;
        DOT16(w2w, f);
        r2c[net][ch] = (a0 + a1) + (a2 + a3);
      }
      BAR();
      if (p < 63) {
        const int p2 = p + 1, j2 = p2 & 7;
        float v = 0.f;
        if (j2 > 0) {   // same row: W tap = h0(p), just written pre-B1
          const float4 f = FRAG(&h0row[net][cur][j + 1][0]);
          float a0 = 0.f, a1 = 0.f, a2 = 0.f, a3 = 0.f;
          DOT16(w1w, f);
          v = (a0 + a1) + (a2 + a3);
        }
        r1c[p2 & 1][net][ch] = v;
      }
      BAR();
    }
  }

  BAR();   // join: yb complete (incl. y(63))

  // copy-out: y from net-0's yb
  if (tid < 256) {
    const int c = tid >> 6, p = tid & 63;
    out[(b*4 + c)*64 + p] = yb[0][(p >> 3) + 1][(p & 7) + 1][c];
  }
}

extern "C" void kernel_launch(void* const* d_in, const int* in_sizes, int n_in,
                              void* d_out, int out_size, void* d_ws, size_t ws_size,
                              hipStream_t stream) {
  (void)in_sizes; (void)n_in; (void)out_size; (void)d_ws; (void)ws_size;
  made_ar_decode_k<<<dim3(32), dim3(NT), 0, stream>>>(
      (const float*)d_in[0],
      (const float*)d_in[1],  (const float*)d_in[2],
      (const float*)d_in[3],  (const float*)d_in[4],
      (const float*)d_in[5],  (const float*)d_in[6],
      (const float*)d_in[7],  (const float*)d_in[8],
      (const float*)d_in[9],  (const float*)d_in[10],
      (const float*)d_in[11], (const float*)d_in[12],
      (const float*)d_in[13], (const float*)d_in[14],
      (const float*)d_in[15], (const float*)d_in[16],
      (float*)d_out);
}